// Round 17
// baseline (1975.042 us; speedup 1.0000x reference)
//
#include <hip/hip_runtime.h>

// LSTM  B=64 T=512 D=256 H=512, fp32 in/out.
// Persistent kernel: 4 clusters x 32 WGs (128 WGs, proven residency),
// 16 batches/cluster, 16 h-cols/WG.
// R15: NO flags, NO drain, NO poll. Publish h as tagged u64 {tag=t+1, 2xbf16}
// fire-and-forget; consumer overlaps out-store + zbuild + x-prefetch, then
// sleeps a calibrated ~0.65us (covers store propagation to the coherence
// point), then gathers ONCE (16 u64, coalesced) and retries only stale slots
// (rare if the delay is right; correctness never depends on timing -- tags +
// distance-2 ping-pong bound the skew, see proof below). Chain per step
// collapses from 3 serialized RTs (drain, flag, gather) to ~1 (gather).
// Control experiment: R8 = same structure WITH flags+immediate gather = 1961us;
// R6 = drain+flag+poll+gather = 1520us.
// Local structure: wave-owns-coltile, in-wave gate transpose, XOR-swizzled
// z ping-pong, B-frags pinned in VGPRs. ONE barrier/step.
//
// Overwrite-safety (distance-2, no flags): publish of h(s) goes to slot s&1.
// A consumer reading h(t+1) (slot (t+1)&1) could only be raced by a producer
// writing h(t+3) (same parity). To publish h(t+3) that WG must have completed
// step t+2, i.e. gathered h(t+2) with ALL tags == t+2, which requires every
// WG (incl. this consumer) to have published h(t+2) -- which happens only
// AFTER the consumer finished gathering h(t+1). Contradiction => safe.

#define T_   512
#define D_   256
#define H_   512
#define NCL  4            // clusters
#define WPC  32           // workgroups per cluster
#define BPC  16           // batches per cluster
#define NKT  24           // K tiles of 32 (24*32 = 768 = D_+H_)
#define ZW   768          // z row width in u16 (XOR-swizzled, no pad)
#define PRE_SLEEPS 3      // 3 x s_sleep(8) ~ 0.64us: cover publish propagation

typedef __attribute__((ext_vector_type(8)))  short  short8;
typedef __attribute__((ext_vector_type(4)))  float  f32x4;
typedef __attribute__((ext_vector_type(4)))  float  float4_;
typedef unsigned short ushort_t;
typedef unsigned int   uint_t;
typedef unsigned long long u64_t;

__device__ __forceinline__ ushort_t f2bf(float f) {           // RNE f32->bf16
    unsigned int u = __float_as_uint(f);
    u += 0x7FFFu + ((u >> 16) & 1u);
    return (ushort_t)(u >> 16);
}
__device__ __forceinline__ float sigm_(float x) { return 1.0f / (1.0f + __expf(-x)); }
__device__ __forceinline__ float tanh_(float x) {
    float a = fabsf(x);
    float e = __expf(-2.0f * a);
    float r = (1.0f - e) / (1.0f + e);
    return copysignf(r, x);
}

// z swizzle: (row r, col c) lives at u16 index r*ZW + ((c>>3 ^ (r&7))<<3) + (c&7)

// build x-part of z: thread (bx,ch) -> row bx, cols ch*16..+16 (blocks 2ch, 2ch+1)
__device__ __forceinline__ void zbuild_x1(ushort_t* zbuf, int bx, int ch,
                                          float4_ xr0, float4_ xr1,
                                          float4_ xr2, float4_ xr3)
{
    short8 a0, a1;
#pragma unroll
    for (int e = 0; e < 4; ++e) {
        a0[e]     = (short)f2bf(xr0[e]);
        a0[4 + e] = (short)f2bf(xr1[e]);
        a1[e]     = (short)f2bf(xr2[e]);
        a1[4 + e] = (short)f2bf(xr3[e]);
    }
    const int s = bx & 7;
    *(short8*)(zbuf + bx * ZW + (((ch * 2    ) ^ s) << 3)) = a0;
    *(short8*)(zbuf + bx * ZW + (((ch * 2 + 1) ^ s) << 3)) = a1;
}

__global__ __launch_bounds__(256, 1)
void lstm_persistent(const float* __restrict__ x,
                     const float* __restrict__ Wf, const float* __restrict__ bf_,
                     const float* __restrict__ Wi, const float* __restrict__ bi_,
                     const float* __restrict__ Wo, const float* __restrict__ bo_,
                     const float* __restrict__ Wc, const float* __restrict__ bc_,
                     float* __restrict__ out,
                     u64_t* __restrict__ hexch)   // [2][NCL][BPC][256] {tag, hi|lo}
{
    __shared__ ushort_t w_lds[4 * NKT * 512];     // 98304 B (B-frag order)
    __shared__ ushort_t z2[2][16 * ZW];           // 49152 B (z ping-pong, swizzled)
    __shared__ float    gate_lds[4][16][20];      //  5120 B (per-wave transpose)
    __shared__ float    bias_lds[64];             //   256 B   (total 152832)

    const int tid  = threadIdx.x;
    const int lane = tid & 63;
    const int wv   = tid >> 6;          // wave 0..3 = col-tile owner
    const int cl   = blockIdx.x >> 5;   // cluster 0..3
    const int w    = blockIdx.x & 31;   // wg-in-cluster 0..31
    const int b0   = cl * BPC;          // first batch
    const int hc0  = w * 16;            // first h-col (global)

    // ---- one-time: repack W slice (fp32 global -> bf16 LDS, B-frag order) ----
    // frag: lane l holds B[k = kt*32 + (l>>4)*8 + j][n = ct*16 + (l&15)], j=0..7
    for (int idx = tid; idx < 4 * NKT * 64; idx += 256) {
        int blk   = idx >> 6;           // 0..95
        int ln    = idx & 63;
        int ct    = blk / NKT;
        int kt    = blk % NKT;
        int j     = ct * 16 + (ln & 15);   // gemm col 0..63  (j = hc*4 + g)
        int hc    = j >> 2, g = j & 3;
        int gcol  = hc0 + hc;
        const float* Wsrc = (g == 0) ? Wf : ((g == 1) ? Wi : ((g == 2) ? Wo : Wc));
        int krow0 = kt * 32 + (ln >> 4) * 8;
        short8 v;
#pragma unroll
        for (int jj = 0; jj < 8; ++jj)
            v[jj] = (short)f2bf(Wsrc[(size_t)(krow0 + jj) * H_ + gcol]);
        *(short8*)(w_lds + blk * 512 + ln * 8) = v;
    }
    if (tid < 64) {
        int g = tid & 3, hc = tid >> 2;
        const float* bsrc = (g == 0) ? bf_ : ((g == 1) ? bi_ : ((g == 2) ? bo_ : bc_));
        bias_lds[tid] = bsrc[hc0 + hc];
    }

    // ---- persistent thread mappings ----
    const int bx = tid & 15, ch = tid >> 4;   // z-build / gather mapping
    const int l15 = lane & 15, lk = lane >> 4;
    const int hidx = hc0 + wv * 4 + lk;       // gates/publish: (batch=l15, hcol=hidx)
    const float* xbase = x + (size_t)(b0 + bx) * (T_ * D_) + ch * 16;

    // load x(0), build z(0) = [x(0) | h=0]
    float4_ xr0, xr1, xr2, xr3;
    {
        const float4_* p = (const float4_*)xbase;
        xr0 = p[0]; xr1 = p[1]; xr2 = p[2]; xr3 = p[3];
    }
    zbuild_x1(z2[0], bx, ch, xr0, xr1, xr2, xr3);
    {
        const int zblk0 = 32 + (tid >> 2), zoff2 = (tid & 3) * 2;
#pragma unroll
        for (int r = 0; r < 16; ++r)
            *(uint_t*)(z2[0] + r * ZW + ((zblk0 ^ (r & 7)) << 3) + zoff2) = 0u;
    }
    __syncthreads();   // w_lds, bias, z(0) ready

    // ---- hoist this wave's 24 B-fragments (col-tile wv) into registers ----
    short8 Bf[NKT];
#pragma unroll
    for (int kt = 0; kt < NKT; ++kt)
        Bf[kt] = *(const short8*)(w_lds + (wv * NKT + kt) * 512 + lane * 8);
    asm volatile("" ::: "memory");   // pin Bf in VGPRs (w_lds "may change")

    u64_t* hex0 = hexch + ((size_t)0 * NCL + cl) * (BPC * 256);
    u64_t* hex1 = hexch + ((size_t)1 * NCL + cl) * (BPC * 256);

    float c_reg = 0.0f;
    const int s7 = l15 & 7;
    const int blk0 = 32 + (tid >> 2), off2 = (tid & 3) * 2;   // gather unpack
    const size_t po = (size_t)l15 * 256 + (hidx >> 1);        // publish offset

    for (int t = 0; t < T_; ++t) {
        // ---- prefetch x(t+1): completes during MFMA; no drain anywhere ----
        if (t + 1 < T_) {
            const float4_* p = (const float4_*)(xbase + (size_t)(t + 1) * D_);
            xr0 = p[0]; xr1 = p[1]; xr2 = p[2]; xr3 = p[3];
        }

        // ---- MFMA: full K (24 kt), this wave's col-tile; 4-acc ILP ----
        const ushort_t* zr = z2[t & 1] + l15 * ZW;
        f32x4 ac0 = {0.f,0.f,0.f,0.f}, ac1 = {0.f,0.f,0.f,0.f};
        f32x4 ac2 = {0.f,0.f,0.f,0.f}, ac3 = {0.f,0.f,0.f,0.f};
#pragma unroll
        for (int kt = 0; kt < NKT; kt += 4) {
            short8 a0 = *(const short8*)(zr + ((((kt + 0) * 4 + lk) ^ s7) << 3));
            short8 a1 = *(const short8*)(zr + ((((kt + 1) * 4 + lk) ^ s7) << 3));
            short8 a2 = *(const short8*)(zr + ((((kt + 2) * 4 + lk) ^ s7) << 3));
            short8 a3 = *(const short8*)(zr + ((((kt + 3) * 4 + lk) ^ s7) << 3));
            ac0 = __builtin_amdgcn_mfma_f32_16x16x32_bf16(a0, Bf[kt + 0], ac0, 0, 0, 0);
            ac1 = __builtin_amdgcn_mfma_f32_16x16x32_bf16(a1, Bf[kt + 1], ac1, 0, 0, 0);
            ac2 = __builtin_amdgcn_mfma_f32_16x16x32_bf16(a2, Bf[kt + 2], ac2, 0, 0, 0);
            ac3 = __builtin_amdgcn_mfma_f32_16x16x32_bf16(a3, Bf[kt + 3], ac3, 0, 0, 0);
        }
        f32x4 acc = (ac0 + ac1) + (ac2 + ac3);

        // ---- in-wave transpose: acc (batch=lk*4+i, gemmcol=l15) -> per-lane gates ----
        *(f32x4*)&gate_lds[wv][l15][lk * 4] = acc;
        asm volatile("s_waitcnt lgkmcnt(0)" ::: "memory");
        __builtin_amdgcn_sched_barrier(0);

        float pre[4];
#pragma unroll
        for (int g = 0; g < 4; ++g)
            pre[g] = bias_lds[(wv * 4 + lk) * 4 + g] + gate_lds[wv][lk * 4 + g][l15];

        float fg = sigm_(pre[0]);
        float ig = sigm_(pre[1]);
        float og = sigm_(pre[2]);
        float cc = tanh_(pre[3]);
        c_reg = fmaf(c_reg, fg, cc * ig);
        float hout = og * tanh_(c_reg);

        // ---- publish h(t+1): tagged u64 pairs, even-lk lanes, FIRE-AND-FORGET ----
        const uint_t want = (uint_t)(t + 1);
        float hpart = __shfl_xor(hout, 16);   // partner holds hidx^1
        if (!(lk & 1)) {
            uint_t pk = ((uint_t)f2bf(hpart) << 16) | (uint_t)f2bf(hout);
            u64_t v64 = ((u64_t)want << 32) | (u64_t)pk;
            u64_t* hp = (((t + 1) & 1) ? hex1 : hex0) + po;
            __hip_atomic_store(hp, v64, __ATOMIC_RELAXED, __HIP_MEMORY_SCOPE_AGENT);
        }

        // ---- overlapped local work while the publish propagates ----
        out[((size_t)(b0 + l15) * T_ + t) * H_ + hidx] = hout;

        if (t + 1 < T_) {
            ushort_t* zn = z2[(t + 1) & 1];
            zbuild_x1(zn, bx, ch, xr0, xr1, xr2, xr3);

            // ---- calibrated delay: publish (all WGs ~synchronized by barrier
            //      cadence) needs ~0.7-0.9us to reach the coherence point ----
#pragma unroll
            for (int sl = 0; sl < PRE_SLEEPS; ++sl)
                __builtin_amdgcn_s_sleep(8);

            // ---- single gather: 16 tagged u64, coalesced; retry stale only ----
            const u64_t* hs = (((t + 1) & 1) ? hex1 : hex0);
            u64_t hv[16];
#pragma unroll
            for (int b = 0; b < 16; ++b)
                hv[b] = __hip_atomic_load(hs + b * 256 + tid,
                                          __ATOMIC_RELAXED, __HIP_MEMORY_SCOPE_AGENT);
            uint_t mask = 0xffffu;
            for (;;) {
#pragma unroll
                for (int b = 0; b < 16; ++b)
                    if (((mask >> b) & 1u) && (uint_t)(hv[b] >> 32) == want) {
                        *(uint_t*)(zn + b * ZW + ((blk0 ^ (b & 7)) << 3) + off2) =
                            (uint_t)hv[b];
                        mask &= ~(1u << b);
                    }
                if (!mask) break;
                __builtin_amdgcn_s_sleep(2);
#pragma unroll
                for (int b = 0; b < 16; ++b)
                    if ((mask >> b) & 1u)
                        hv[b] = __hip_atomic_load(hs + b * 256 + tid,
                                                  __ATOMIC_RELAXED,
                                                  __HIP_MEMORY_SCOPE_AGENT);
            }
        }

        __syncthreads();   // (B) z(t+1) ready; z(t) free next iter. The
        // implicit vmcnt(0) drains publish/out acks here -- long since back.
    }
}

extern "C" void kernel_launch(void* const* d_in, const int* in_sizes, int n_in,
                              void* d_out, int out_size, void* d_ws, size_t ws_size,
                              hipStream_t stream) {
    const float* x  = (const float*)d_in[0];
    const float* Wf = (const float*)d_in[1];
    const float* bf = (const float*)d_in[2];
    const float* Wi = (const float*)d_in[3];
    const float* bi = (const float*)d_in[4];
    const float* Wo = (const float*)d_in[5];
    const float* bo = (const float*)d_in[6];
    const float* Wc = (const float*)d_in[7];
    const float* bc = (const float*)d_in[8];
    float* out = (float*)d_out;

    // workspace: hexch [2][4][16][256] u64 = 512 KB -- zeroed per launch so
    // replays can't short-circuit on stale tags (tags start invalid).
    u64_t* hexch = (u64_t*)d_ws;
    hipMemsetAsync(d_ws, 0, (size_t)2 * NCL * BPC * 256 * sizeof(u64_t), stream);

    lstm_persistent<<<dim3(NCL * WPC), dim3(256), 0, stream>>>(
        x, Wf, bf, Wi, bi, Wo, bo, Wc, bc, out, hexch);
}

// Round 18
// 1357.738 us; speedup vs baseline: 1.4547x; 1.4547x over previous
//
#include <hip/hip_runtime.h>

// LSTM  B=64 T=512 D=256 H=512, fp32 in/out.
// Persistent kernel: 4 clusters x 32 WGs (128 WGs, proven residency),
// 16 batches/cluster, 16 h-cols/WG.
// R16 = R6 (best: 1520us) + ONE change: the x-part of step t+1's GEMM
// (K-tiles 0..7, no h dependency) is computed INSIDE the poll window --
// after zbuild(t+1)+barrier, before the flag poll -- carrying the partial
// accumulator in registers across the iteration boundary. The h-part
// (K-tiles 8..23) continues that accumulator at top-of-step. This converts
// ~0.3us of s_sleep idle into useful MFMA. Protocol identical to R6:
// publish u32 pairs -> vmcnt(0) -> barrier A -> per-WG flag -> out+x-issue
// -> single-128B-line sleep-paced poll (lanes<32, divergent exit) ->
// 16-u32 coalesced gather -> barrier. 3 barriers/step (A, B1, B2).
// Local structure: wave-owns-coltile, in-wave gate transpose, XOR-swizzled
// z ping-pong, B-frags pinned in VGPRs.

#define T_   512
#define D_   256
#define H_   512
#define NCL  4            // clusters
#define WPC  32           // workgroups per cluster
#define BPC  16           // batches per cluster
#define NKT  24           // K tiles of 32 (24*32 = 768 = D_+H_); 0..7 = x, 8..23 = h
#define ZW   768          // z row width in u16 (XOR-swizzled, no pad)

typedef __attribute__((ext_vector_type(8)))  short  short8;
typedef __attribute__((ext_vector_type(4)))  float  f32x4;
typedef __attribute__((ext_vector_type(4)))  float  float4_;
typedef unsigned short ushort_t;
typedef unsigned int   uint_t;

__device__ __forceinline__ ushort_t f2bf(float f) {           // RNE f32->bf16
    unsigned int u = __float_as_uint(f);
    u += 0x7FFFu + ((u >> 16) & 1u);
    return (ushort_t)(u >> 16);
}
__device__ __forceinline__ float sigm_(float x) { return 1.0f / (1.0f + __expf(-x)); }
__device__ __forceinline__ float tanh_(float x) {
    float a = fabsf(x);
    float e = __expf(-2.0f * a);
    float r = (1.0f - e) / (1.0f + e);
    return copysignf(r, x);
}

// z swizzle: (row r, col c) lives at u16 index r*ZW + ((c>>3 ^ (r&7))<<3) + (c&7)

// build x-part of z: thread (bx,ch) -> row bx, cols ch*16..+16 (blocks 2ch, 2ch+1)
__device__ __forceinline__ void zbuild_x1(ushort_t* zbuf, int bx, int ch,
                                          float4_ xr0, float4_ xr1,
                                          float4_ xr2, float4_ xr3)
{
    short8 a0, a1;
#pragma unroll
    for (int e = 0; e < 4; ++e) {
        a0[e]     = (short)f2bf(xr0[e]);
        a0[4 + e] = (short)f2bf(xr1[e]);
        a1[e]     = (short)f2bf(xr2[e]);
        a1[4 + e] = (short)f2bf(xr3[e]);
    }
    const int s = bx & 7;
    *(short8*)(zbuf + bx * ZW + (((ch * 2    ) ^ s) << 3)) = a0;
    *(short8*)(zbuf + bx * ZW + (((ch * 2 + 1) ^ s) << 3)) = a1;
}

__global__ __launch_bounds__(256, 1)
void lstm_persistent(const float* __restrict__ x,
                     const float* __restrict__ Wf, const float* __restrict__ bf_,
                     const float* __restrict__ Wi, const float* __restrict__ bi_,
                     const float* __restrict__ Wo, const float* __restrict__ bo_,
                     const float* __restrict__ Wc, const float* __restrict__ bc_,
                     float* __restrict__ out,
                     uint_t* __restrict__ flags,   // [NCL][WPC] per-WG, monotonic
                     uint_t* __restrict__ hexch)   // [2][NCL][BPC][256] u32 {h1<<16|h0}
{
    __shared__ ushort_t w_lds[4 * NKT * 512];     // 98304 B (B-frag order)
    __shared__ ushort_t z2[2][16 * ZW];           // 49152 B (z ping-pong, swizzled)
    __shared__ float    gate_lds[4][16][20];      //  5120 B (per-wave transpose)
    __shared__ float    bias_lds[64];             //   256 B   (total 152832)

    const int tid  = threadIdx.x;
    const int lane = tid & 63;
    const int wv   = tid >> 6;          // wave 0..3 = col-tile owner
    const int cl   = blockIdx.x >> 5;   // cluster 0..3
    const int w    = blockIdx.x & 31;   // wg-in-cluster 0..31
    const int b0   = cl * BPC;          // first batch
    const int hc0  = w * 16;            // first h-col (global)

    // ---- one-time: repack W slice (fp32 global -> bf16 LDS, B-frag order) ----
    // frag: lane l holds B[k = kt*32 + (l>>4)*8 + j][n = ct*16 + (l&15)], j=0..7
    for (int idx = tid; idx < 4 * NKT * 64; idx += 256) {
        int blk   = idx >> 6;           // 0..95
        int ln    = idx & 63;
        int ct    = blk / NKT;
        int kt    = blk % NKT;
        int j     = ct * 16 + (ln & 15);   // gemm col 0..63  (j = hc*4 + g)
        int hc    = j >> 2, g = j & 3;
        int gcol  = hc0 + hc;
        const float* Wsrc = (g == 0) ? Wf : ((g == 1) ? Wi : ((g == 2) ? Wo : Wc));
        int krow0 = kt * 32 + (ln >> 4) * 8;
        short8 v;
#pragma unroll
        for (int jj = 0; jj < 8; ++jj)
            v[jj] = (short)f2bf(Wsrc[(size_t)(krow0 + jj) * H_ + gcol]);
        *(short8*)(w_lds + blk * 512 + ln * 8) = v;
    }
    if (tid < 64) {
        int g = tid & 3, hc = tid >> 2;
        const float* bsrc = (g == 0) ? bf_ : ((g == 1) ? bi_ : ((g == 2) ? bo_ : bc_));
        bias_lds[tid] = bsrc[hc0 + hc];
    }

    // ---- persistent thread mappings ----
    const int bx = tid & 15, ch = tid >> 4;   // z-build / gather mapping
    const int l15 = lane & 15, lk = lane >> 4;
    const int hidx = hc0 + wv * 4 + lk;       // gates/publish: (batch=l15, hcol=hidx)
    const float* xbase = x + (size_t)(b0 + bx) * (T_ * D_) + ch * 16;

    // load x(0), build z(0) = [x(0) | h=0]
    float4_ xr0, xr1, xr2, xr3;
    {
        const float4_* p = (const float4_*)xbase;
        xr0 = p[0]; xr1 = p[1]; xr2 = p[2]; xr3 = p[3];
    }
    zbuild_x1(z2[0], bx, ch, xr0, xr1, xr2, xr3);
    {
        const int zblk0 = 32 + (tid >> 2), zoff2 = (tid & 3) * 2;
#pragma unroll
        for (int r = 0; r < 16; ++r)
            *(uint_t*)(z2[0] + r * ZW + ((zblk0 ^ (r & 7)) << 3) + zoff2) = 0u;
    }
    __syncthreads();   // w_lds, bias, z(0) ready

    // ---- hoist this wave's 24 B-fragments (col-tile wv) into registers ----
    short8 Bf[NKT];
#pragma unroll
    for (int kt = 0; kt < NKT; ++kt)
        Bf[kt] = *(const short8*)(w_lds + (wv * NKT + kt) * 512 + lane * 8);
    asm volatile("" ::: "memory");   // pin Bf in VGPRs (w_lds "may change")

    uint_t* flags_cl = flags + cl * WPC;
    uint_t* hex0 = hexch + ((size_t)0 * NCL + cl) * (BPC * 256);
    uint_t* hex1 = hexch + ((size_t)1 * NCL + cl) * (BPC * 256);

    float c_reg = 0.0f;
    const int s7 = l15 & 7;
    const int blk0 = 32 + (tid >> 2), off2 = (tid & 3) * 2;   // gather unpack
    const size_t po = (size_t)l15 * 256 + (hidx >> 1);        // publish offset

    // ---- x-part MFMA for t=0 (carried accumulator) ----
    f32x4 axA = {0.f,0.f,0.f,0.f}, axB = {0.f,0.f,0.f,0.f};
    {
        const ushort_t* zr0 = z2[0] + l15 * ZW;
#pragma unroll
        for (int kt = 0; kt < 8; kt += 2) {
            short8 a0 = *(const short8*)(zr0 + ((((kt + 0) * 4 + lk) ^ s7) << 3));
            short8 a1 = *(const short8*)(zr0 + ((((kt + 1) * 4 + lk) ^ s7) << 3));
            axA = __builtin_amdgcn_mfma_f32_16x16x32_bf16(a0, Bf[kt + 0], axA, 0, 0, 0);
            axB = __builtin_amdgcn_mfma_f32_16x16x32_bf16(a1, Bf[kt + 1], axB, 0, 0, 0);
        }
    }

    for (int t = 0; t < T_; ++t) {
        // ---- prefetch x(t+1): completes during h-MFMA ----
        if (t + 1 < T_) {
            const float4_* p = (const float4_*)(xbase + (size_t)(t + 1) * D_);
            xr0 = p[0]; xr1 = p[1]; xr2 = p[2]; xr3 = p[3];
        }

        // ---- h-part MFMA (kt 8..23), continuing from carried x-part acc ----
        const ushort_t* zr = z2[t & 1] + l15 * ZW;
        f32x4 ac0 = axA, ac1 = axB;
        f32x4 ac2 = {0.f,0.f,0.f,0.f}, ac3 = {0.f,0.f,0.f,0.f};
#pragma unroll
        for (int kt = 8; kt < NKT; kt += 4) {
            short8 a0 = *(const short8*)(zr + ((((kt + 0) * 4 + lk) ^ s7) << 3));
            short8 a1 = *(const short8*)(zr + ((((kt + 1) * 4 + lk) ^ s7) << 3));
            short8 a2 = *(const short8*)(zr + ((((kt + 2) * 4 + lk) ^ s7) << 3));
            short8 a3 = *(const short8*)(zr + ((((kt + 3) * 4 + lk) ^ s7) << 3));
            ac0 = __builtin_amdgcn_mfma_f32_16x16x32_bf16(a0, Bf[kt + 0], ac0, 0, 0, 0);
            ac1 = __builtin_amdgcn_mfma_f32_16x16x32_bf16(a1, Bf[kt + 1], ac1, 0, 0, 0);
            ac2 = __builtin_amdgcn_mfma_f32_16x16x32_bf16(a2, Bf[kt + 2], ac2, 0, 0, 0);
            ac3 = __builtin_amdgcn_mfma_f32_16x16x32_bf16(a3, Bf[kt + 3], ac3, 0, 0, 0);
        }
        f32x4 acc = (ac0 + ac1) + (ac2 + ac3);

        // ---- in-wave transpose: acc (batch=lk*4+i, gemmcol=l15) -> per-lane gates ----
        *(f32x4*)&gate_lds[wv][l15][lk * 4] = acc;
        asm volatile("s_waitcnt lgkmcnt(0)" ::: "memory");
        __builtin_amdgcn_sched_barrier(0);

        float pre[4];
#pragma unroll
        for (int g = 0; g < 4; ++g)
            pre[g] = bias_lds[(wv * 4 + lk) * 4 + g] + gate_lds[wv][lk * 4 + g][l15];

        float fg = sigm_(pre[0]);
        float ig = sigm_(pre[1]);
        float og = sigm_(pre[2]);
        float cc = tanh_(pre[3]);
        c_reg = fmaf(c_reg, fg, cc * ig);
        float hout = og * tanh_(c_reg);

        // ---- publish h(t+1): packed u32 pair, even-lk lanes ----
        float hpart = __shfl_xor(hout, 16);   // partner holds hidx^1
        if (!(lk & 1)) {
            uint_t pk = ((uint_t)f2bf(hpart) << 16) | (uint_t)f2bf(hout);
            uint_t* hp = (((t + 1) & 1) ? hex1 : hex0) + po;
            __hip_atomic_store(hp, pk, __ATOMIC_RELAXED, __HIP_MEMORY_SCOPE_AGENT);
        }

        // ---- clean drain, then release flag (R6 protocol, untouched) ----
        asm volatile("s_waitcnt vmcnt(0)" ::: "memory");
        __builtin_amdgcn_sched_barrier(0);
        __syncthreads();   // (A) all waves' publishes at coherence point
        if (tid == 0)
            __hip_atomic_store(flags_cl + w, (uint_t)(t + 1),
                               __ATOMIC_RELAXED, __HIP_MEMORY_SCOPE_AGENT);

        // ---- off-critical-path: out store ----
        out[((size_t)(b0 + l15) * T_ + t) * H_ + hidx] = hout;

        if (t + 1 < T_) {
            ushort_t* zn = z2[(t + 1) & 1];

            // ---- zbuild x(t+1) (x prefetched at top of step) ----
            zbuild_x1(zn, bx, ch, xr0, xr1, xr2, xr3);
            __syncthreads();   // (B1) zn x-part complete across waves

            // ---- x-part MFMA for t+1: fills the poll window ----
            axA = (f32x4){0.f,0.f,0.f,0.f};
            axB = (f32x4){0.f,0.f,0.f,0.f};
            {
                const ushort_t* znr = zn + l15 * ZW;
#pragma unroll
                for (int kt = 0; kt < 8; kt += 2) {
                    short8 a0 = *(const short8*)(znr + ((((kt + 0) * 4 + lk) ^ s7) << 3));
                    short8 a1 = *(const short8*)(znr + ((((kt + 1) * 4 + lk) ^ s7) << 3));
                    axA = __builtin_amdgcn_mfma_f32_16x16x32_bf16(a0, Bf[kt + 0], axA, 0, 0, 0);
                    axB = __builtin_amdgcn_mfma_f32_16x16x32_bf16(a1, Bf[kt + 1], axB, 0, 0, 0);
                }
            }

            // ---- sleep-paced flag poll: ONE 128B line, divergent per-lane exit ----
            if (lane < WPC) {
                const uint_t* fp = flags_cl + lane;
                while (__hip_atomic_load(fp, __ATOMIC_RELAXED,
                                         __HIP_MEMORY_SCOPE_AGENT) <= (uint_t)t)
                    __builtin_amdgcn_s_sleep(1);
            }

            // ---- gather: 16 coalesced u32 (fresh: flags imply drained) ----
            const uint_t* hs = (((t + 1) & 1) ? hex1 : hex0);
            uint_t hv[16];
#pragma unroll
            for (int q = 0; q < 16; ++q)
                hv[q] = __hip_atomic_load(hs + q * 256 + tid,
                                          __ATOMIC_RELAXED, __HIP_MEMORY_SCOPE_AGENT);
            // thread holds h-cols {2*tid, 2*tid+1} for batches q=0..15
#pragma unroll
            for (int q = 0; q < 16; ++q)
                *(uint_t*)(zn + q * ZW + ((blk0 ^ (q & 7)) << 3) + off2) = hv[q];
        }

        __syncthreads();   // (B2) z(t+1) h-part ready; z(t) free next iter
    }
}

extern "C" void kernel_launch(void* const* d_in, const int* in_sizes, int n_in,
                              void* d_out, int out_size, void* d_ws, size_t ws_size,
                              hipStream_t stream) {
    const float* x  = (const float*)d_in[0];
    const float* Wf = (const float*)d_in[1];
    const float* bf = (const float*)d_in[2];
    const float* Wi = (const float*)d_in[3];
    const float* bi = (const float*)d_in[4];
    const float* Wo = (const float*)d_in[5];
    const float* bo = (const float*)d_in[6];
    const float* Wc = (const float*)d_in[7];
    const float* bc = (const float*)d_in[8];
    float* out = (float*)d_out;

    // workspace: [0, 512)        flags [4][32] u32 -- zeroed per launch
    //            [4096, +131072) hexch [2][4][16][256] u32 (gated by flags+drain)
    uint_t* flags = (uint_t*)d_ws;
    uint_t* hexch = (uint_t*)((char*)d_ws + 4096);

    hipMemsetAsync(d_ws, 0, 4096, stream);   // flags

    lstm_persistent<<<dim3(NCL * WPC), dim3(256), 0, stream>>>(
        x, Wf, bf, Wi, bi, Wo, bo, Wc, bc, out, flags, hexch);
}